// Round 1
// baseline (1313.377 us; speedup 1.0000x reference)
//
#include <hip/hip_runtime.h>

// GrCNN: B=32, L=128, D=256. 127 sequential levels.
// Strategy (round 1): fp16 MFMA, fused [left|right] K=512 GEMM vs
// W_cat=[Wl;Wr] (+16-col gate tile = [Gl;Gr] padded), multi-launch
// (1 prep + 1 init + 127 step kernels). Whole sentence + W-slice staged
// in LDS (swizzled). Each block = (batch b, col-group g) -> sole writer
// of its 32 output cols; gates computed redundantly per group.

#define B_ 32
#define L_ 128
#define D_ 256
#define K_ 512          // 2*D (left|right concat)
#define NG 8            // column groups
#define GC 32           // central cols per group
#define WC 48           // cols per group incl 16-col gate tile
#define LOG2E 1.4426950408889634f

typedef _Float16 half8 __attribute__((ext_vector_type(8)));
typedef float f32x4 __attribute__((ext_vector_type(4)));

// ---- prep: build WT[g][WC][K_] fp16, column-major-per-col (col j -> 512 k) ----
__global__ void prep_wt(const float* __restrict__ Wl, const float* __restrict__ Wr,
                        const float* __restrict__ Gl, const float* __restrict__ Gr,
                        _Float16* __restrict__ WT) {
    int g = blockIdx.x / WC;
    int j = blockIdx.x % WC;
    for (int k = threadIdx.x; k < K_; k += 256) {
        float v;
        if (j < GC) {
            int c = g * GC + j;
            v = (k < D_) ? Wl[k * D_ + c] : Wr[(k - D_) * D_ + c];
        } else {
            int jj = j - GC;
            v = 0.f;
            if (jj < 3) v = (k < D_) ? Gl[k * 3 + jj] : Gr[(k - D_) * 3 + jj];
        }
        WT[((size_t)(g * WC + j)) * K_ + k] = (_Float16)v;
    }
}

// ---- init: convert x -> fp16 state, and level-0 max (over all 128 rows) ----
__global__ void init_state(const float* __restrict__ x, _Float16* __restrict__ S,
                           float* __restrict__ out) {
    int b = blockIdx.x;
    int c = threadIdx.x;  // 256
    float m = -3.4e38f;
    for (int l = 0; l < L_; ++l) {
        float v = x[((size_t)b * L_ + l) * D_ + c];
        S[((size_t)b * L_ + l) * D_ + c] = (_Float16)v;
        m = fmaxf(m, v);
    }
    out[(size_t)b * L_ * D_ + c] = m;  // out[b][0][c]
}

// LDS: staged state (129 rows * 512B, swizzled) + W slice (48KB, swizzled) + wave maxes
#define SST_BYTES ((L_ + 1) * D_ * 2)     // 66048
#define WST_BYTES (WC * K_ * 2)           // 49152
#define LDS_BYTES (SST_BYTES + WST_BYTES + 4 * GC * 4)

__global__ __launch_bounds__(256) void step_k(
    const _Float16* __restrict__ Scur, _Float16* __restrict__ Snext,
    const _Float16* __restrict__ WT, const float* __restrict__ Wb,
    const float* __restrict__ Gb, float* __restrict__ out, int t)
{
    __shared__ alignas(16) char lds[LDS_BYTES];
    char* sst = lds;                       // swizzled state
    char* wst = lds + SST_BYTES;           // swizzled W slice
    float* lmax = (float*)(lds + SST_BYTES + WST_BYTES);  // [4][GC]

    const int tid = threadIdx.x;
    const int b = blockIdx.x >> 3, g = blockIdx.x & 7;
    const int n = (L_ - 1) - t;            // rows computed this level
    const _Float16* sb = Scur + (size_t)b * L_ * D_;

    // stage state rows [0, n+1): row stride 512B, swizzle off ^= ((off>>9)&7)<<4
    int nch = (n + 1) * (D_ * 2 / 16);     // 16B chunks
    for (int ch = tid; ch < nch; ch += 256) {
        int row = ch >> 5, kc = ch & 31;
        half8 v = *(const half8*)(sb + row * D_ + kc * 8);
        int off = row * 512 + kc * 16;
        off ^= ((off >> 9) & 7) << 4;
        *(half8*)(sst + off) = v;
    }
    // stage W slice: col j stride 1024B, swizzle by (j&7)<<4
    const _Float16* wg = WT + (size_t)g * WC * K_;
    for (int ch = tid; ch < WC * K_ / 8; ch += 256) {
        int j = ch >> 6, kc = ch & 63;
        half8 v = *(const half8*)(wg + j * K_ + kc * 8);
        int off = j * 1024 + kc * 16;
        off ^= ((off >> 10) & 7) << 4;
        *(half8*)(wst + off) = v;
    }
    __syncthreads();

    const int w = tid >> 6, l = tid & 63;
    const int lr = l & 15, q = l >> 4;
    const int r0 = w * 32;                 // wave's 32-row slab

    f32x4 acc[2][3] = {};                  // [m-half][ntile: c0-15, c16-31, gate]
    if (r0 < n) {
        #pragma unroll
        for (int s = 0; s < 16; ++s) {
            int ko = s * 64 + q * 16;
            int a0off = (r0 + lr) * 512 + ko;      a0off ^= ((a0off >> 9) & 7) << 4;
            int a1off = (r0 + 16 + lr) * 512 + ko; a1off ^= ((a1off >> 9) & 7) << 4;
            half8 a0 = *(const half8*)(sst + a0off);
            half8 a1 = *(const half8*)(sst + a1off);
            int sw = (lr & 7) << 4;
            half8 b0 = *(const half8*)(wst + (((lr) * 1024 + ko) ^ sw));
            half8 b1 = *(const half8*)(wst + (((16 + lr) * 1024 + ko) ^ sw));
            half8 b2 = *(const half8*)(wst + (((32 + lr) * 1024 + ko) ^ sw));
            acc[0][0] = __builtin_amdgcn_mfma_f32_16x16x32_f16(a0, b0, acc[0][0], 0, 0, 0);
            acc[0][1] = __builtin_amdgcn_mfma_f32_16x16x32_f16(a0, b1, acc[0][1], 0, 0, 0);
            acc[0][2] = __builtin_amdgcn_mfma_f32_16x16x32_f16(a0, b2, acc[0][2], 0, 0, 0);
            acc[1][0] = __builtin_amdgcn_mfma_f32_16x16x32_f16(a1, b0, acc[1][0], 0, 0, 0);
            acc[1][1] = __builtin_amdgcn_mfma_f32_16x16x32_f16(a1, b1, acc[1][1], 0, 0, 0);
            acc[1][2] = __builtin_amdgcn_mfma_f32_16x16x32_f16(a1, b2, acc[1][2], 0, 0, 0);
        }
    }

    float vmax0 = -3.4e38f, vmax1 = -3.4e38f;
    if (r0 < n) {
        const float gb0 = Gb[0], gb1 = Gb[1], gb2 = Gb[2];
        const float wb0 = Wb[g * GC + lr];
        const float wb1 = Wb[g * GC + 16 + lr];
        _Float16* snb = Snext + (size_t)b * L_ * D_;
        #pragma unroll
        for (int mh = 0; mh < 2; ++mh) {
            #pragma unroll
            for (int r = 0; r < 4; ++r) {
                int row = r0 + mh * 16 + q * 4 + r;
                // gates: cols 0..2 of gate tile live in lanes (l&48)+{0,1,2}
                float p0 = __shfl(acc[mh][2][r], (l & 48) + 0, 64) + gb0;
                float p1 = __shfl(acc[mh][2][r], (l & 48) + 1, 64) + gb1;
                float p2 = __shfl(acc[mh][2][r], (l & 48) + 2, 64) + gb2;
                if (row < n) {
                    float mg = fmaxf(fmaxf(p0, p1), p2);
                    float e0 = exp2f((p0 - mg) * LOG2E);
                    float e1 = exp2f((p1 - mg) * LOG2E);
                    float e2 = exp2f((p2 - mg) * LOG2E);
                    float inv = __builtin_amdgcn_rcpf(e0 + e1 + e2);
                    float g0 = e0 * inv, g1 = e1 * inv, g2 = e2 * inv;
                    #pragma unroll
                    for (int nt = 0; nt < 2; ++nt) {
                        int c = g * GC + nt * 16 + lr;
                        float pre = acc[mh][nt][r] + (nt ? wb1 : wb0);
                        // tanh(x) = 1 - 2/(e^{2x}+1), inf-safe
                        float ex = exp2f(pre * (2.f * LOG2E));
                        float ce = 1.f - 2.f * __builtin_amdgcn_rcpf(ex + 1.f);
                        int lo = row * 512 + c * 2;       lo ^= ((lo >> 9) & 7) << 4;
                        int ro = (row + 1) * 512 + c * 2; ro ^= ((ro >> 9) & 7) << 4;
                        float lv = (float)*(const _Float16*)(sst + lo);
                        float rv = (float)*(const _Float16*)(sst + ro);
                        float nx = g0 * lv + g1 * ce + g2 * rv;
                        snb[row * D_ + c] = (_Float16)nx;
                        if (nt == 0) vmax0 = fmaxf(vmax0, nx);
                        else         vmax1 = fmaxf(vmax1, nx);
                    }
                }
            }
        }
    }

    // reduce col-max across the 4 q-groups (same l&15 -> same col)
    #pragma unroll
    for (int d = 16; d < 64; d <<= 1) {
        vmax0 = fmaxf(vmax0, __shfl_xor(vmax0, d, 64));
        vmax1 = fmaxf(vmax1, __shfl_xor(vmax1, d, 64));
    }
    if (l < 16) { lmax[w * GC + l] = vmax0; lmax[w * GC + 16 + l] = vmax1; }
    __syncthreads();
    if (tid < GC) {
        float m2 = fmaxf(fmaxf(lmax[tid], lmax[GC + tid]),
                         fmaxf(lmax[2 * GC + tid], lmax[3 * GC + tid]));
        out[((size_t)b * L_ + (t + 1)) * D_ + g * GC + tid] = m2;
    }
}

extern "C" void kernel_launch(void* const* d_in, const int* in_sizes, int n_in,
                              void* d_out, int out_size, void* d_ws, size_t ws_size,
                              hipStream_t stream) {
    const float* x  = (const float*)d_in[0];
    const float* Wl = (const float*)d_in[1];
    const float* Wr = (const float*)d_in[2];
    const float* Wb = (const float*)d_in[3];
    const float* Gl = (const float*)d_in[4];
    const float* Gr = (const float*)d_in[5];
    const float* Gb = (const float*)d_in[6];
    float* out = (float*)d_out;
    char* ws = (char*)d_ws;

    _Float16* SA = (_Float16*)ws;                                  // 2 MB
    _Float16* SB = (_Float16*)(ws + (size_t)2 * 1024 * 1024);      // 2 MB
    _Float16* WT = (_Float16*)(ws + (size_t)4 * 1024 * 1024);      // 384 KB

    prep_wt<<<NG * WC, 256, 0, stream>>>(Wl, Wr, Gl, Gr, WT);
    init_state<<<B_, 256, 0, stream>>>(x, SA, out);

    _Float16* cur = SA;
    _Float16* nxt = SB;
    for (int t = 0; t < L_ - 1; ++t) {
        step_k<<<B_ * NG, 256, 0, stream>>>(cur, nxt, WT, Wb, Gb, out, t);
        _Float16* tmp = cur; cur = nxt; nxt = tmp;
    }
}